// Round 15
// baseline (100.745 us; speedup 1.0000x reference)
//
#include <hip/hip_runtime.h>
#include <hip/hip_bf16.h>
#include <stdint.h>

typedef unsigned short u16;
typedef unsigned int   u32;
typedef short s16x8 __attribute__((ext_vector_type(8)));   // 8 bf16 (4 VGPR)
typedef u16   u16x4 __attribute__((ext_vector_type(4)));
typedef u32   u32x4 __attribute__((ext_vector_type(4)));
typedef float f32x4  __attribute__((ext_vector_type(4)));
typedef float f32x16 __attribute__((ext_vector_type(16)));
typedef float f4     __attribute__((ext_vector_type(4)));

#define MFMA(a,b,c)   __builtin_amdgcn_mfma_f32_16x16x32_bf16((a),(b),(c),0,0,0)
#define MFMA32(a,b,c) __builtin_amdgcn_mfma_f32_32x32x16_bf16((a),(b),(c),0,0,0)

#define BAR()   __builtin_amdgcn_s_barrier()
#define SCHED() __builtin_amdgcn_sched_barrier(0)

#define CS 1024

__device__ __forceinline__ u16 f2b(float f){
  union { float f; unsigned u; } v; v.f = f;
  unsigned r = v.u + 0x7fffu + ((v.u >> 16) & 1u);
  return (u16)(r >> 16);
}

__device__ __forceinline__ u32 cvtpk(float lo, float hi){
  u32 r;
  asm("v_cvt_pk_bf16_f32 %0, %1, %2" : "=v"(r) : "v"(lo), "v"(hi));
  return r;
}

__device__ __forceinline__ float exp2h(float x){
  float r;
  asm("v_exp_f32 %0, %1" : "=v"(r) : "v"(x));
  return r;
}

__device__ __forceinline__ void gll16(const void* g, void* l){
  // async global->LDS, 16B/lane; LDS dst is WAVE-UNIFORM base (HW adds lane*16)
  __builtin_amdgcn_global_load_lds(
      (const __attribute__((address_space(1))) void*)g,
      (__attribute__((address_space(3))) void*)l, 16, 0, 0);
}

// ------------- streaming cast: q|k|v|w_q|w_k|w_v|w_o -> bf16, 8 elem/thread -
__global__ __launch_bounds__(256) void wcast8(
    const float* __restrict__ q,  const float* __restrict__ k,  const float* __restrict__ v,
    const float* __restrict__ wq, const float* __restrict__ wk, const float* __restrict__ wv,
    const float* __restrict__ wo,
    u16* qb, u16* kb, u16* vb, u16* dq, u16* dk, u16* dv, u16* dov){
  const int bx = blockIdx.x;
  const float* s; u16* d; int base;
  if      (bx < 2048){ s = q;  d = qb;  base = bx; }
  else if (bx < 4096){ s = k;  d = kb;  base = bx - 2048; }
  else if (bx < 6144){ s = v;  d = vb;  base = bx - 4096; }
  else if (bx < 6656){ s = wq; d = dq;  base = bx - 6144; }
  else if (bx < 6784){ s = wk; d = dk;  base = bx - 6656; }
  else if (bx < 6912){ s = wv; d = dv;  base = bx - 6784; }
  else               { s = wo; d = dov; base = bx - 6912; }
  int i = base*2048 + threadIdx.x*8;
  f4 v0 = *(const f4*)(s + i);
  f4 v1 = *(const f4*)(s + i + 4);
  u32x4 o; o[0] = cvtpk(v0[0], v0[1]); o[1] = cvtpk(v0[2], v0[3]);
           o[2] = cvtpk(v1[0], v1[1]); o[3] = cvtpk(v1[2], v1[3]);
  *(u32x4*)(d + i) = o;
}

// ---------------- merged Q/K/V projection GEMM: BM=128,BN=128,BK=64 ---------
__global__ __launch_bounds__(256) void qkv_gemm(
    const u16* __restrict__ qa, const u16* __restrict__ ka, const u16* __restrict__ va,
    const u16* __restrict__ wq, const u16* __restrict__ wk, const u16* __restrict__ wv,
    const float* __restrict__ bq, const float* __restrict__ bk, const float* __restrict__ bv,
    u16* Qo, u16* Ko, u16* Vto){
  __shared__ __align__(16) char AsB[2][16*CS];
  __shared__ __align__(16) char BsB[2][16*CS];
  const int tid = threadIdx.x, lane = tid & 63, wid = tid >> 6;
  const int lb = (blockIdx.x & 7) * 48 + (blockIdx.x >> 3);
  const u16* A; const u16* B; const float* bias; int N; float cscale; int bm, bn;
  bool isV = false;
  if (lb < 256)      { A=qa; B=wq; bias=bq; N=1024; cscale=0.18033688011112f; bm=lb>>3;       bn=lb&7; }
  else if (lb < 320) { A=ka; B=wk; bias=bk; N=256;  cscale=1.0f;              bm=(lb-256)>>1; bn=(lb-256)&1; }
  else               { A=va; B=wv; bias=bv; N=256;  cscale=1.0f;              bm=(lb-320)>>1; bn=(lb-320)&1; isV = true; }
  const int wr = wid >> 1, wc = wid & 1;
  const int r15 = lane & 15, kg = lane >> 4;

  const u16* Ag = A + (size_t)bm * 128 * 1024;
  const u16* Bg = B + (size_t)bn * 128 * 1024;
  f32x4 acc[4][4] = {};

  const int rr = lane >> 3;
  const int slot16 = ((lane & 7) ^ rr) << 4;

  auto stage = [&](int buf, int k0){
    #pragma unroll
    for (int i = 0; i < 4; i++){
      int cc = wid + i*4;
      size_t rowoff = (size_t)(cc*8 + rr) * 2048 + (size_t)k0 * 2;
      gll16((const char*)Ag + rowoff + slot16, &AsB[buf][cc*CS]);
      gll16((const char*)Bg + rowoff + slot16, &BsB[buf][cc*CS]);
    }
  };

  const int rb = (r15 >> 3)*CS + (r15 & 7)*128;
  const int r7 = r15 & 7;

  auto compute = [&](int buf){
    #pragma unroll
    for (int h = 0; h < 2; h++){
      s16x8 af[4], bf[4];
      #pragma unroll
      for (int i = 0; i < 4; i++)
        af[i] = *(const s16x8*)(&AsB[buf][(wr*8 + i*2)*CS] + rb + (((h*4 + kg) ^ r7) << 4));
      #pragma unroll
      for (int j = 0; j < 4; j++)
        bf[j] = *(const s16x8*)(&BsB[buf][(wc*8 + j*2)*CS] + rb + (((h*4 + kg) ^ r7) << 4));
      __builtin_amdgcn_s_setprio(1);
      #pragma unroll
      for (int i = 0; i < 4; i++)
        #pragma unroll
        for (int j = 0; j < 4; j++)
          acc[i][j] = MFMA(af[i], bf[j], acc[i][j]);
      __builtin_amdgcn_s_setprio(0);
    }
  };

  stage(0, 0); stage(1, 64);
  for (int t = 0; t < 14; t++){
    asm volatile("s_waitcnt vmcnt(8)" ::: "memory");
    BAR(); SCHED();
    compute(t & 1);
    SCHED(); BAR();
    stage(t & 1, (t + 2)*64);
  }
  asm volatile("s_waitcnt vmcnt(8)" ::: "memory");
  BAR(); SCHED();
  compute(0);
  asm volatile("s_waitcnt vmcnt(0)" ::: "memory");
  BAR(); SCHED();
  compute(1);

  if (isV){
    #pragma unroll
    for (int i = 0; i < 4; i++){
      int row0 = bm*128 + wr*64 + i*16 + kg*4;
      int bb = row0 >> 11, t = row0 & 2047;
      #pragma unroll
      for (int j = 0; j < 4; j++){
        int col = bn*128 + wc*64 + j*16 + r15;
        float bj = bias[col];
        u16x4 vv;
        #pragma unroll
        for (int r = 0; r < 4; r++) vv[r] = f2b(acc[i][j][r] + bj);
        *(u16x4*)&Vto[((size_t)(bb*256 + col) << 11) + t] = vv;
      }
    }
  } else {
    u16* C = (lb < 256) ? Qo : Ko;
    #pragma unroll
    for (int i = 0; i < 4; i++){
      int row = bm*128 + wr*64 + i*16 + kg*4;
      #pragma unroll
      for (int j = 0; j < 4; j++){
        int col = bn*128 + wc*64 + j*16 + r15;
        float bj = bias[col];
        #pragma unroll
        for (int r = 0; r < 4; r++)
          C[(size_t)(row + r)*N + col] = f2b((acc[i][j][r] + bj) * cscale);
      }
    }
  }
}

// ---------------- output projection GEMM: BM=128,BN=128,BK=64 ---------------
// Clone of the proven qkv_gemm loop (32 MFMA/wave/step, 8 gll16/tile,
// counted vmcnt(8) depth-2 pipeline); f32+bias epilogue. 256 blocks
// (= 8 XCDs x 32, bijective swizzle). Halves sequential K-steps/CU vs BM=64.
__global__ __launch_bounds__(256) void gemm_o(const u16* __restrict__ Aw,
                                              const u16* __restrict__ Bw,
                                              const float* __restrict__ bias,
                                              float* __restrict__ Cv){
  __shared__ __align__(16) char AsB[2][16*CS];
  __shared__ __align__(16) char BsB[2][16*CS];
  const int tid = threadIdx.x, lane = tid & 63, wid = tid >> 6;
  const int lb = (blockIdx.x & 7) * 32 + (blockIdx.x >> 3);
  const int bm = lb >> 3, bn = lb & 7;
  const int wr = wid >> 1, wc = wid & 1;
  const int r15 = lane & 15, kg = lane >> 4;
  const u16* Ag = Aw + (size_t)bm * 128 * 1024;
  const u16* Bg = Bw + (size_t)bn * 128 * 1024;
  f32x4 acc[4][4] = {};

  const int rr = lane >> 3;
  const int slot16 = ((lane & 7) ^ rr) << 4;

  auto stage = [&](int buf, int k0){
    #pragma unroll
    for (int i = 0; i < 4; i++){
      int cc = wid + i*4;
      size_t rowoff = (size_t)(cc*8 + rr) * 2048 + (size_t)k0 * 2;
      gll16((const char*)Ag + rowoff + slot16, &AsB[buf][cc*CS]);
      gll16((const char*)Bg + rowoff + slot16, &BsB[buf][cc*CS]);
    }
  };

  const int rb = (r15 >> 3)*CS + (r15 & 7)*128;
  const int r7 = r15 & 7;

  auto compute = [&](int buf){
    #pragma unroll
    for (int h = 0; h < 2; h++){
      s16x8 af[4], bf[4];
      #pragma unroll
      for (int i = 0; i < 4; i++)
        af[i] = *(const s16x8*)(&AsB[buf][(wr*8 + i*2)*CS] + rb + (((h*4 + kg) ^ r7) << 4));
      #pragma unroll
      for (int j = 0; j < 4; j++)
        bf[j] = *(const s16x8*)(&BsB[buf][(wc*8 + j*2)*CS] + rb + (((h*4 + kg) ^ r7) << 4));
      __builtin_amdgcn_s_setprio(1);
      #pragma unroll
      for (int i = 0; i < 4; i++)
        #pragma unroll
        for (int j = 0; j < 4; j++)
          acc[i][j] = MFMA(af[i], bf[j], acc[i][j]);
      __builtin_amdgcn_s_setprio(0);
    }
  };

  stage(0, 0); stage(1, 64);
  for (int t = 0; t < 14; t++){
    asm volatile("s_waitcnt vmcnt(8)" ::: "memory");
    BAR(); SCHED();
    compute(t & 1);
    SCHED(); BAR();
    stage(t & 1, (t + 2)*64);
  }
  asm volatile("s_waitcnt vmcnt(8)" ::: "memory");
  BAR(); SCHED();
  compute(0);
  asm volatile("s_waitcnt vmcnt(0)" ::: "memory");
  BAR(); SCHED();
  compute(1);

  #pragma unroll
  for (int i = 0; i < 4; i++){
    int row = bm*128 + wr*64 + i*16 + kg*4;
    #pragma unroll
    for (int j = 0; j < 4; j++){
      int col = bn*128 + wc*64 + j*16 + r15;
      float bj = bias[col];
      #pragma unroll
      for (int r = 0; r < 4; r++)
        Cv[(size_t)(row + r)*1024 + col] = acc[i][j][r] + bj;
    }
  }
}

// ---------------- flash attention: R13-proven (UNTOUCHED) --------------------
// 8 waves (2 KV-split groups x 4), KVBLK=64, counted-vmcnt double buffer,
// 2 barriers/tile. Three source-level restructures (R11/R12/R14) of this
// compute core each produced small schedule-dependent corruption despite
// provable per-thread equivalence — do not restructure without disasm access.
__global__ __launch_bounds__(512, 4) void attn_fwd(const u16* __restrict__ Qp,
                                                   const u16* __restrict__ Kp,
                                                   const u16* __restrict__ Vt,
                                                   u16* __restrict__ Op){
  __shared__ u16 Ks[2][2][64*64];   // [group][buf][t][d], swizzled source
  __shared__ u16 Vs[2][2][64*64];   // [group][buf][d][t], swizzled source
  const int tid = threadIdx.x, lane = tid & 63, w = tid >> 6;
  const int wg = w & 3, g = w >> 2;
  const int bx = blockIdx.x;
  const int qt = bx & 15, h = (bx >> 4) & 15, b = bx >> 8;
  const int kvh = h >> 2;
  const int l31 = lane & 31, hh = lane >> 5;
  const int srow = lane >> 3;
  const int scol16 = ((lane & 7) ^ srow) << 4;

  // Q fragments (B-operand): lane holds Q[q=l31][d = db*16 + hh*8 + j]
  const size_t qrow0 = (size_t)(b*2048 + qt*128 + wg*32 + l31) << 10;
  s16x8 qf[4];
  #pragma unroll
  for (int db = 0; db < 4; db++)
    qf[db] = *(const s16x8*)(Qp + qrow0 + h*64 + db*16 + hh*8);

  f32x16 oacc[2] = {};
  const f32x16 ZERO = {};
  float ls0 = 0.f, ls1 = 0.f, ls2 = 0.f, ls3 = 0.f;

  // constant-stride GLOBAL staging pointers:
  // group g's tile n = (2n+g)*64; K advances 128 rows x 512B, V 128 t x 2B.
  const int row0 = wg*8 + srow;
  const char* kp0 = (const char*)Kp + ((size_t)(b*2048 + g*64 + row0) << 9) + kvh*128 + scol16;
  const char* kp1 = kp0 + (32 << 9);
  const char* vp0 = (const char*)Vt + ((size_t)((b*4 + kvh)*64 + row0) << 12) + g*128 + scol16;
  const char* vp1 = vp0 + ((size_t)32 << 12);

  auto stage = [&](int buf){
    gll16(kp0, (char*)&Ks[g][buf][0] + wg*1024);
    gll16(kp1, (char*)&Ks[g][buf][0] + wg*1024 + 4096);
    gll16(vp0, (char*)&Vs[g][buf][0] + wg*1024);
    gll16(vp1, (char*)&Vs[g][buf][0] + wg*1024 + 4096);
    kp0 += 65536; kp1 += 65536; vp0 += 256; vp1 += 256;
  };

  stage(0);

  for (int it = 0; it < 16; it++){
    const int cur = it & 1;
    if (it + 1 < 16){
      stage(cur ^ 1);                                  // buf cur^1 free since bar2(it-1)
      asm volatile("s_waitcnt vmcnt(4)" ::: "memory"); // tile it done; it+1 in flight
    } else {
      asm volatile("s_waitcnt vmcnt(0)" ::: "memory");
    }
    BAR(); SCHED();

    // --- S^T = K Q^T : sacc[kb2] = S[k=kb2*32+(r&3)+4hh+8(r>>2)][q=l31] ---
    f32x16 sacc[2];
    __builtin_amdgcn_s_setprio(1);
    #pragma unroll
    for (int kb2 = 0; kb2 < 2; kb2++){
      #pragma unroll
      for (int db = 0; db < 4; db++){
        int row = kb2*32 + l31;
        int slot = (db*2 + hh) ^ (row & 7);
        s16x8 kf = *(const s16x8*)((const char*)&Ks[g][cur][0] + row*128 + slot*16);
        sacc[kb2] = MFMA32(kf, qf[db], (db == 0) ? ZERO : sacc[kb2]);
      }
    }
    __builtin_amdgcn_s_setprio(0);

    // --- p = exp2(s) (log2e/8 pre-folded into Q); pack; 4-chain row sums ---
    u32 W[2][4][2];
    #pragma unroll
    for (int kb2 = 0; kb2 < 2; kb2++){
      #pragma unroll
      for (int a = 0; a < 4; a++){
        float p0 = exp2h(sacc[kb2][4*a + 0]);
        float p1 = exp2h(sacc[kb2][4*a + 1]);
        float p2 = exp2h(sacc[kb2][4*a + 2]);
        float p3 = exp2h(sacc[kb2][4*a + 3]);
        W[kb2][a][0] = cvtpk(p0, p1);
        W[kb2][a][1] = cvtpk(p2, p3);
        if (kb2 == 0){ ls0 += p0 + p1; ls1 += p2 + p3; }
        else         { ls2 += p0 + p1; ls3 += p2 + p3; }
      }
    }

    // --- build PV A-frags via permlane32_swap: pa[kq]=P[q=l31][kq*16+hh*8+j] ---
    s16x8 pa[4];
    #pragma unroll
    for (int kq = 0; kq < 4; kq++){
      const int kb2 = kq >> 1, c = kq & 1;
      u32x4 dw;
      #pragma unroll
      for (int pp = 0; pp < 2; pp++){
        u32 x = W[kb2][2*c][pp], y = W[kb2][2*c + 1][pp];
        asm volatile("v_permlane32_swap_b32 %0, %1" : "+v"(x), "+v"(y));
        dw[pp] = x; dw[2 + pp] = y;     // x'={x_lo,y_lo}, y'={x_hi,y_hi}
      }
      pa[kq] = *(const s16x8*)&dw;
    }

    // --- O += P V : oacc[dblk] = O[q=(r&3)+4hh+8(r>>2)][d=dblk*32+l31] ---
    __builtin_amdgcn_s_setprio(1);
    #pragma unroll
    for (int dblk = 0; dblk < 2; dblk++){
      #pragma unroll
      for (int kq = 0; kq < 4; kq++){
        int row = dblk*32 + l31;
        int slot = (kq*2 + hh) ^ (row & 7);
        s16x8 vf = *(const s16x8*)((const char*)&Vs[g][cur][0] + row*128 + slot*16);
        oacc[dblk] = MFMA32(pa[kq], vf, oacc[dblk]);
      }
    }
    __builtin_amdgcn_s_setprio(0);
    SCHED(); BAR();                     // protect buf cur before next stage
  }
  __syncthreads();                      // full drain before LDS reuse below

  // --- merge the two KV-halves via LDS (reuse Ks/Vs), then store ---
  float lsum = (ls0 + ls1) + (ls2 + ls3);
  float rsum = lsum + __shfl_xor(lsum, 32, 64);    // row sum for q=l31 (own half)
  float* Om = (float*)&Ks[0][0][0];                // 4 waves x 32q x 64d = 32KB
  float* Ls = (float*)&Vs[0][0][0];                // 128 floats
  if (g == 1){
    #pragma unroll
    for (int reg = 0; reg < 16; reg++){
      int q = (reg & 3) + 4*hh + 8*(reg >> 2);
      #pragma unroll
      for (int dblk = 0; dblk < 2; dblk++)
        Om[(wg*32 + q)*64 + dblk*32 + l31] = oacc[dblk][reg];
    }
    if (hh == 0) Ls[wg*32 + l31] = rsum;
  }
  __syncthreads();
  if (g == 0){
    rsum += Ls[wg*32 + l31];
    float rinv = __builtin_amdgcn_rcpf(rsum);
    const size_t obase = (size_t)(b*2048 + qt*128 + wg*32) << 10;
    #pragma unroll
    for (int reg = 0; reg < 16; reg++){
      const int qrow = (reg & 3) + 4*hh + 8*(reg >> 2);
      float rq = __shfl(rinv, qrow, 64);
      #pragma unroll
      for (int dblk = 0; dblk < 2; dblk++){
        float v = (oacc[dblk][reg] + Om[(wg*32 + qrow)*64 + dblk*32 + l31]) * rq;
        Op[obase + ((size_t)qrow << 10) + h*64 + dblk*32 + l31] = f2b(v);
      }
    }
  }
}

// ---------------- launch ----------------
extern "C" void kernel_launch(void* const* d_in, const int* in_sizes, int n_in,
                              void* d_out, int out_size, void* d_ws, size_t ws_size,
                              hipStream_t stream){
  const float* query = (const float*)d_in[0];
  const float* key   = (const float*)d_in[1];
  const float* value = (const float*)d_in[2];
  const float* w_q   = (const float*)d_in[3];
  const float* b_q   = (const float*)d_in[4];
  const float* w_k   = (const float*)d_in[5];
  const float* b_k   = (const float*)d_in[6];
  const float* w_v   = (const float*)d_in[7];
  const float* b_v   = (const float*)d_in[8];
  const float* w_o   = (const float*)d_in[9];
  const float* b_o   = (const float*)d_in[10];

  char* ws = (char*)d_ws;
  size_t off = 0;
  u16* wqb = (u16*)(ws + off); off += (size_t)1024*1024*2;
  u16* wkb = (u16*)(ws + off); off += (size_t)256*1024*2;
  u16* wvb = (u16*)(ws + off); off += (size_t)256*1024*2;
  u16* wob = (u16*)(ws + off); off += (size_t)1024*1024*2;
  u16* Qw  = (u16*)(ws + off); off += (size_t)4096*1024*2;
  u16* Kw  = (u16*)(ws + off); off += (size_t)4096*256*2;
  u16* Vtw = (u16*)(ws + off); off += (size_t)4096*256*2;
  u16* AOw = (u16*)(ws + off); off += (size_t)4096*1024*2;
  u16* kb  = (u16*)(ws + off); off += (size_t)4096*1024*2;
  u16* vb  = (u16*)(ws + off); off += (size_t)4096*1024*2;   // total ~43 MB
  u16* qb  = AOw;   // alias: qb dead before attn_fwd writes AOw

  wcast8<<<7424, 256, 0, stream>>>(query, key, value, w_q, w_k, w_v, w_o,
                                   qb, kb, vb, wqb, wkb, wvb, wob);

  qkv_gemm<<<384, 256, 0, stream>>>(qb, kb, vb, wqb, wkb, wvb,
                                    b_q, b_k, b_v, Qw, Kw, Vtw);

  attn_fwd<<<512, 512, 0, stream>>>(Qw, Kw, Vtw, AOw);

  gemm_o<<<256, 256, 0, stream>>>(AOw, wob, b_o, (float*)d_out);
}

// Round 16
// 97.658 us; speedup vs baseline: 1.0316x; 1.0316x over previous
//
#include <hip/hip_runtime.h>
#include <hip/hip_bf16.h>
#include <stdint.h>

typedef unsigned short u16;
typedef unsigned int   u32;
typedef short s16x8 __attribute__((ext_vector_type(8)));   // 8 bf16 (4 VGPR)
typedef u16   u16x4 __attribute__((ext_vector_type(4)));
typedef u32   u32x4 __attribute__((ext_vector_type(4)));
typedef float f32x4  __attribute__((ext_vector_type(4)));
typedef float f32x16 __attribute__((ext_vector_type(16)));
typedef float f4     __attribute__((ext_vector_type(4)));

#define MFMA(a,b,c)   __builtin_amdgcn_mfma_f32_16x16x32_bf16((a),(b),(c),0,0,0)
#define MFMA32(a,b,c) __builtin_amdgcn_mfma_f32_32x32x16_bf16((a),(b),(c),0,0,0)

#define BAR()   __builtin_amdgcn_s_barrier()
#define SCHED() __builtin_amdgcn_sched_barrier(0)

#define CS 1024

__device__ __forceinline__ u16 f2b(float f){
  union { float f; unsigned u; } v; v.f = f;
  unsigned r = v.u + 0x7fffu + ((v.u >> 16) & 1u);
  return (u16)(r >> 16);
}

__device__ __forceinline__ u32 cvtpk(float lo, float hi){
  u32 r;
  asm("v_cvt_pk_bf16_f32 %0, %1, %2" : "=v"(r) : "v"(lo), "v"(hi));
  return r;
}

__device__ __forceinline__ float exp2h(float x){
  float r;
  asm("v_exp_f32 %0, %1" : "=v"(r) : "v"(x));
  return r;
}

__device__ __forceinline__ void gll16(const void* g, void* l){
  // async global->LDS, 16B/lane; LDS dst is WAVE-UNIFORM base (HW adds lane*16)
  __builtin_amdgcn_global_load_lds(
      (const __attribute__((address_space(1))) void*)g,
      (__attribute__((address_space(3))) void*)l, 16, 0, 0);
}

// ------------- streaming cast: q|k|v|w_q|w_k|w_v|w_o -> bf16, 8 elem/thread -
__global__ __launch_bounds__(256) void wcast8(
    const float* __restrict__ q,  const float* __restrict__ k,  const float* __restrict__ v,
    const float* __restrict__ wq, const float* __restrict__ wk, const float* __restrict__ wv,
    const float* __restrict__ wo,
    u16* qb, u16* kb, u16* vb, u16* dq, u16* dk, u16* dv, u16* dov){
  const int bx = blockIdx.x;
  const float* s; u16* d; int base;
  if      (bx < 2048){ s = q;  d = qb;  base = bx; }
  else if (bx < 4096){ s = k;  d = kb;  base = bx - 2048; }
  else if (bx < 6144){ s = v;  d = vb;  base = bx - 4096; }
  else if (bx < 6656){ s = wq; d = dq;  base = bx - 6144; }
  else if (bx < 6784){ s = wk; d = dk;  base = bx - 6656; }
  else if (bx < 6912){ s = wv; d = dv;  base = bx - 6784; }
  else               { s = wo; d = dov; base = bx - 6912; }
  int i = base*2048 + threadIdx.x*8;
  f4 v0 = *(const f4*)(s + i);
  f4 v1 = *(const f4*)(s + i + 4);
  u32x4 o; o[0] = cvtpk(v0[0], v0[1]); o[1] = cvtpk(v0[2], v0[3]);
           o[2] = cvtpk(v1[0], v1[1]); o[3] = cvtpk(v1[2], v1[3]);
  *(u32x4*)(d + i) = o;
}

// ---------------- merged Q/K/V projection GEMM: BM=128,BN=128,BK=64 ---------
__global__ __launch_bounds__(256) void qkv_gemm(
    const u16* __restrict__ qa, const u16* __restrict__ ka, const u16* __restrict__ va,
    const u16* __restrict__ wq, const u16* __restrict__ wk, const u16* __restrict__ wv,
    const float* __restrict__ bq, const float* __restrict__ bk, const float* __restrict__ bv,
    u16* Qo, u16* Ko, u16* Vto){
  __shared__ __align__(16) char AsB[2][16*CS];
  __shared__ __align__(16) char BsB[2][16*CS];
  const int tid = threadIdx.x, lane = tid & 63, wid = tid >> 6;
  const int lb = (blockIdx.x & 7) * 48 + (blockIdx.x >> 3);
  const u16* A; const u16* B; const float* bias; int N; float cscale; int bm, bn;
  bool isV = false;
  if (lb < 256)      { A=qa; B=wq; bias=bq; N=1024; cscale=0.18033688011112f; bm=lb>>3;       bn=lb&7; }
  else if (lb < 320) { A=ka; B=wk; bias=bk; N=256;  cscale=1.0f;              bm=(lb-256)>>1; bn=(lb-256)&1; }
  else               { A=va; B=wv; bias=bv; N=256;  cscale=1.0f;              bm=(lb-320)>>1; bn=(lb-320)&1; isV = true; }
  const int wr = wid >> 1, wc = wid & 1;
  const int r15 = lane & 15, kg = lane >> 4;

  const u16* Ag = A + (size_t)bm * 128 * 1024;
  const u16* Bg = B + (size_t)bn * 128 * 1024;
  f32x4 acc[4][4] = {};

  const int rr = lane >> 3;
  const int slot16 = ((lane & 7) ^ rr) << 4;

  auto stage = [&](int buf, int k0){
    #pragma unroll
    for (int i = 0; i < 4; i++){
      int cc = wid + i*4;
      size_t rowoff = (size_t)(cc*8 + rr) * 2048 + (size_t)k0 * 2;
      gll16((const char*)Ag + rowoff + slot16, &AsB[buf][cc*CS]);
      gll16((const char*)Bg + rowoff + slot16, &BsB[buf][cc*CS]);
    }
  };

  const int rb = (r15 >> 3)*CS + (r15 & 7)*128;
  const int r7 = r15 & 7;

  auto compute = [&](int buf){
    #pragma unroll
    for (int h = 0; h < 2; h++){
      s16x8 af[4], bf[4];
      #pragma unroll
      for (int i = 0; i < 4; i++)
        af[i] = *(const s16x8*)(&AsB[buf][(wr*8 + i*2)*CS] + rb + (((h*4 + kg) ^ r7) << 4));
      #pragma unroll
      for (int j = 0; j < 4; j++)
        bf[j] = *(const s16x8*)(&BsB[buf][(wc*8 + j*2)*CS] + rb + (((h*4 + kg) ^ r7) << 4));
      __builtin_amdgcn_s_setprio(1);
      #pragma unroll
      for (int i = 0; i < 4; i++)
        #pragma unroll
        for (int j = 0; j < 4; j++)
          acc[i][j] = MFMA(af[i], bf[j], acc[i][j]);
      __builtin_amdgcn_s_setprio(0);
    }
  };

  stage(0, 0); stage(1, 64);
  for (int t = 0; t < 14; t++){
    asm volatile("s_waitcnt vmcnt(8)" ::: "memory");
    BAR(); SCHED();
    compute(t & 1);
    SCHED(); BAR();
    stage(t & 1, (t + 2)*64);
  }
  asm volatile("s_waitcnt vmcnt(8)" ::: "memory");
  BAR(); SCHED();
  compute(0);
  asm volatile("s_waitcnt vmcnt(0)" ::: "memory");
  BAR(); SCHED();
  compute(1);

  if (isV){
    #pragma unroll
    for (int i = 0; i < 4; i++){
      int row0 = bm*128 + wr*64 + i*16 + kg*4;
      int bb = row0 >> 11, t = row0 & 2047;
      #pragma unroll
      for (int j = 0; j < 4; j++){
        int col = bn*128 + wc*64 + j*16 + r15;
        float bj = bias[col];
        u16x4 vv;
        #pragma unroll
        for (int r = 0; r < 4; r++) vv[r] = f2b(acc[i][j][r] + bj);
        *(u16x4*)&Vto[((size_t)(bb*256 + col) << 11) + t] = vv;
      }
    }
  } else {
    u16* C = (lb < 256) ? Qo : Ko;
    #pragma unroll
    for (int i = 0; i < 4; i++){
      int row = bm*128 + wr*64 + i*16 + kg*4;
      #pragma unroll
      for (int j = 0; j < 4; j++){
        int col = bn*128 + wc*64 + j*16 + r15;
        float bj = bias[col];
        #pragma unroll
        for (int r = 0; r < 4; r++)
          C[(size_t)(row + r)*N + col] = f2b((acc[i][j][r] + bj) * cscale);
      }
    }
  }
}

// ---------------- output projection GEMM: BM=64,BN=128,BK=64 (R13-proven) ---
// 16 K-steps; 6 gll16/wave/tile -> steady vmcnt(6). 512 blocks = 2 blk/CU
// (BM=128/grid-256 variant regressed: 1 blk/CU exposes the barrier drains).
__global__ __launch_bounds__(256) void gemm_o(const u16* __restrict__ Aw,
                                              const u16* __restrict__ Bw,
                                              const float* __restrict__ bias,
                                              float* __restrict__ Cv){
  __shared__ __align__(16) char AsB[2][8*CS];
  __shared__ __align__(16) char BsB[2][16*CS];
  const int tid = threadIdx.x, lane = tid & 63, wid = tid >> 6;
  const int lb = (blockIdx.x & 7) * 64 + (blockIdx.x >> 3);
  const int bm = lb >> 3, bn = lb & 7;
  const int wr = wid >> 1, wc = wid & 1;
  const int r15 = lane & 15, kg = lane >> 4;
  const u16* Ag = Aw + (size_t)bm * 64 * 1024;
  const u16* Bg = Bw + (size_t)bn * 128 * 1024;
  f32x4 acc[2][4] = {};

  const int rr = lane >> 3;
  const int slot16 = ((lane & 7) ^ rr) << 4;

  auto stage = [&](int buf, int k0){
    #pragma unroll
    for (int i = 0; i < 2; i++){
      int cc = wid + i*4;
      size_t rowoff = (size_t)(cc*8 + rr) * 2048 + (size_t)k0 * 2;
      gll16((const char*)Ag + rowoff + slot16, &AsB[buf][cc*CS]);
    }
    #pragma unroll
    for (int i = 0; i < 4; i++){
      int cc = wid + i*4;
      size_t rowoff = (size_t)(cc*8 + rr) * 2048 + (size_t)k0 * 2;
      gll16((const char*)Bg + rowoff + slot16, &BsB[buf][cc*CS]);
    }
  };

  const int rb = (r15 >> 3)*CS + (r15 & 7)*128;
  const int r7 = r15 & 7;

  auto compute = [&](int buf){
    #pragma unroll
    for (int h = 0; h < 2; h++){
      s16x8 af[2], bf[4];
      #pragma unroll
      for (int i = 0; i < 2; i++)
        af[i] = *(const s16x8*)(&AsB[buf][(wr*4 + i*2)*CS] + rb + (((h*4 + kg) ^ r7) << 4));
      #pragma unroll
      for (int j = 0; j < 4; j++)
        bf[j] = *(const s16x8*)(&BsB[buf][(wc*8 + j*2)*CS] + rb + (((h*4 + kg) ^ r7) << 4));
      __builtin_amdgcn_s_setprio(1);
      #pragma unroll
      for (int i = 0; i < 2; i++)
        #pragma unroll
        for (int j = 0; j < 4; j++)
          acc[i][j] = MFMA(af[i], bf[j], acc[i][j]);
      __builtin_amdgcn_s_setprio(0);
    }
  };

  stage(0, 0); stage(1, 64);
  for (int t = 0; t < 14; t++){
    asm volatile("s_waitcnt vmcnt(6)" ::: "memory");
    BAR(); SCHED();
    compute(t & 1);
    SCHED(); BAR();
    stage(t & 1, (t + 2)*64);
  }
  asm volatile("s_waitcnt vmcnt(6)" ::: "memory");
  BAR(); SCHED();
  compute(0);
  asm volatile("s_waitcnt vmcnt(0)" ::: "memory");
  BAR(); SCHED();
  compute(1);

  #pragma unroll
  for (int i = 0; i < 2; i++){
    int row = bm*64 + wr*32 + i*16 + kg*4;
    #pragma unroll
    for (int j = 0; j < 4; j++){
      int col = bn*128 + wc*64 + j*16 + r15;
      float bj = bias[col];
      #pragma unroll
      for (int r = 0; r < 4; r++)
        Cv[(size_t)(row + r)*1024 + col] = acc[i][j][r] + bj;
    }
  }
}

// ---------------- flash attention: R13-proven (UNTOUCHED) --------------------
// 8 waves (2 KV-split groups x 4), KVBLK=64, counted-vmcnt double buffer,
// 2 barriers/tile. Three source-level restructures (R11/R12/R14) of this
// compute core each produced small schedule-dependent corruption despite
// provable per-thread equivalence — do not restructure without disasm access.
__global__ __launch_bounds__(512, 4) void attn_fwd(const u16* __restrict__ Qp,
                                                   const u16* __restrict__ Kp,
                                                   const u16* __restrict__ Vt,
                                                   u16* __restrict__ Op){
  __shared__ u16 Ks[2][2][64*64];   // [group][buf][t][d], swizzled source
  __shared__ u16 Vs[2][2][64*64];   // [group][buf][d][t], swizzled source
  const int tid = threadIdx.x, lane = tid & 63, w = tid >> 6;
  const int wg = w & 3, g = w >> 2;
  const int bx = blockIdx.x;
  const int qt = bx & 15, h = (bx >> 4) & 15, b = bx >> 8;
  const int kvh = h >> 2;
  const int l31 = lane & 31, hh = lane >> 5;
  const int srow = lane >> 3;
  const int scol16 = ((lane & 7) ^ srow) << 4;

  // Q fragments (B-operand): lane holds Q[q=l31][d = db*16 + hh*8 + j]
  const size_t qrow0 = (size_t)(b*2048 + qt*128 + wg*32 + l31) << 10;
  s16x8 qf[4];
  #pragma unroll
  for (int db = 0; db < 4; db++)
    qf[db] = *(const s16x8*)(Qp + qrow0 + h*64 + db*16 + hh*8);

  f32x16 oacc[2] = {};
  const f32x16 ZERO = {};
  float ls0 = 0.f, ls1 = 0.f, ls2 = 0.f, ls3 = 0.f;

  // constant-stride GLOBAL staging pointers:
  // group g's tile n = (2n+g)*64; K advances 128 rows x 512B, V 128 t x 2B.
  const int row0 = wg*8 + srow;
  const char* kp0 = (const char*)Kp + ((size_t)(b*2048 + g*64 + row0) << 9) + kvh*128 + scol16;
  const char* kp1 = kp0 + (32 << 9);
  const char* vp0 = (const char*)Vt + ((size_t)((b*4 + kvh)*64 + row0) << 12) + g*128 + scol16;
  const char* vp1 = vp0 + ((size_t)32 << 12);

  auto stage = [&](int buf){
    gll16(kp0, (char*)&Ks[g][buf][0] + wg*1024);
    gll16(kp1, (char*)&Ks[g][buf][0] + wg*1024 + 4096);
    gll16(vp0, (char*)&Vs[g][buf][0] + wg*1024);
    gll16(vp1, (char*)&Vs[g][buf][0] + wg*1024 + 4096);
    kp0 += 65536; kp1 += 65536; vp0 += 256; vp1 += 256;
  };

  stage(0);

  for (int it = 0; it < 16; it++){
    const int cur = it & 1;
    if (it + 1 < 16){
      stage(cur ^ 1);                                  // buf cur^1 free since bar2(it-1)
      asm volatile("s_waitcnt vmcnt(4)" ::: "memory"); // tile it done; it+1 in flight
    } else {
      asm volatile("s_waitcnt vmcnt(0)" ::: "memory");
    }
    BAR(); SCHED();

    // --- S^T = K Q^T : sacc[kb2] = S[k=kb2*32+(r&3)+4hh+8(r>>2)][q=l31] ---
    f32x16 sacc[2];
    __builtin_amdgcn_s_setprio(1);
    #pragma unroll
    for (int kb2 = 0; kb2 < 2; kb2++){
      #pragma unroll
      for (int db = 0; db < 4; db++){
        int row = kb2*32 + l31;
        int slot = (db*2 + hh) ^ (row & 7);
        s16x8 kf = *(const s16x8*)((const char*)&Ks[g][cur][0] + row*128 + slot*16);
        sacc[kb2] = MFMA32(kf, qf[db], (db == 0) ? ZERO : sacc[kb2]);
      }
    }
    __builtin_amdgcn_s_setprio(0);

    // --- p = exp2(s) (log2e/8 pre-folded into Q); pack; 4-chain row sums ---
    u32 W[2][4][2];
    #pragma unroll
    for (int kb2 = 0; kb2 < 2; kb2++){
      #pragma unroll
      for (int a = 0; a < 4; a++){
        float p0 = exp2h(sacc[kb2][4*a + 0]);
        float p1 = exp2h(sacc[kb2][4*a + 1]);
        float p2 = exp2h(sacc[kb2][4*a + 2]);
        float p3 = exp2h(sacc[kb2][4*a + 3]);
        W[kb2][a][0] = cvtpk(p0, p1);
        W[kb2][a][1] = cvtpk(p2, p3);
        if (kb2 == 0){ ls0 += p0 + p1; ls1 += p2 + p3; }
        else         { ls2 += p0 + p1; ls3 += p2 + p3; }
      }
    }

    // --- build PV A-frags via permlane32_swap: pa[kq]=P[q=l31][kq*16+hh*8+j] ---
    s16x8 pa[4];
    #pragma unroll
    for (int kq = 0; kq < 4; kq++){
      const int kb2 = kq >> 1, c = kq & 1;
      u32x4 dw;
      #pragma unroll
      for (int pp = 0; pp < 2; pp++){
        u32 x = W[kb2][2*c][pp], y = W[kb2][2*c + 1][pp];
        asm volatile("v_permlane32_swap_b32 %0, %1" : "+v"(x), "+v"(y));
        dw[pp] = x; dw[2 + pp] = y;     // x'={x_lo,y_lo}, y'={x_hi,y_hi}
      }
      pa[kq] = *(const s16x8*)&dw;
    }

    // --- O += P V : oacc[dblk] = O[q=(r&3)+4hh+8(r>>2)][d=dblk*32+l31] ---
    __builtin_amdgcn_s_setprio(1);
    #pragma unroll
    for (int dblk = 0; dblk < 2; dblk++){
      #pragma unroll
      for (int kq = 0; kq < 4; kq++){
        int row = dblk*32 + l31;
        int slot = (kq*2 + hh) ^ (row & 7);
        s16x8 vf = *(const s16x8*)((const char*)&Vs[g][cur][0] + row*128 + slot*16);
        oacc[dblk] = MFMA32(pa[kq], vf, oacc[dblk]);
      }
    }
    __builtin_amdgcn_s_setprio(0);
    SCHED(); BAR();                     // protect buf cur before next stage
  }
  __syncthreads();                      // full drain before LDS reuse below

  // --- merge the two KV-halves via LDS (reuse Ks/Vs), then store ---
  float lsum = (ls0 + ls1) + (ls2 + ls3);
  float rsum = lsum + __shfl_xor(lsum, 32, 64);    // row sum for q=l31 (own half)
  float* Om = (float*)&Ks[0][0][0];                // 4 waves x 32q x 64d = 32KB
  float* Ls = (float*)&Vs[0][0][0];                // 128 floats
  if (g == 1){
    #pragma unroll
    for (int reg = 0; reg < 16; reg++){
      int q = (reg & 3) + 4*hh + 8*(reg >> 2);
      #pragma unroll
      for (int dblk = 0; dblk < 2; dblk++)
        Om[(wg*32 + q)*64 + dblk*32 + l31] = oacc[dblk][reg];
    }
    if (hh == 0) Ls[wg*32 + l31] = rsum;
  }
  __syncthreads();
  if (g == 0){
    rsum += Ls[wg*32 + l31];
    float rinv = __builtin_amdgcn_rcpf(rsum);
    const size_t obase = (size_t)(b*2048 + qt*128 + wg*32) << 10;
    #pragma unroll
    for (int reg = 0; reg < 16; reg++){
      const int qrow = (reg & 3) + 4*hh + 8*(reg >> 2);
      float rq = __shfl(rinv, qrow, 64);
      #pragma unroll
      for (int dblk = 0; dblk < 2; dblk++){
        float v = (oacc[dblk][reg] + Om[(wg*32 + qrow)*64 + dblk*32 + l31]) * rq;
        Op[obase + ((size_t)qrow << 10) + h*64 + dblk*32 + l31] = f2b(v);
      }
    }
  }
}

// ---------------- launch ----------------
extern "C" void kernel_launch(void* const* d_in, const int* in_sizes, int n_in,
                              void* d_out, int out_size, void* d_ws, size_t ws_size,
                              hipStream_t stream){
  const float* query = (const float*)d_in[0];
  const float* key   = (const float*)d_in[1];
  const float* value = (const float*)d_in[2];
  const float* w_q   = (const float*)d_in[3];
  const float* b_q   = (const float*)d_in[4];
  const float* w_k   = (const float*)d_in[5];
  const float* b_k   = (const float*)d_in[6];
  const float* w_v   = (const float*)d_in[7];
  const float* b_v   = (const float*)d_in[8];
  const float* w_o   = (const float*)d_in[9];
  const float* b_o   = (const float*)d_in[10];

  char* ws = (char*)d_ws;
  size_t off = 0;
  u16* wqb = (u16*)(ws + off); off += (size_t)1024*1024*2;
  u16* wkb = (u16*)(ws + off); off += (size_t)256*1024*2;
  u16* wvb = (u16*)(ws + off); off += (size_t)256*1024*2;
  u16* wob = (u16*)(ws + off); off += (size_t)1024*1024*2;
  u16* Qw  = (u16*)(ws + off); off += (size_t)4096*1024*2;
  u16* Kw  = (u16*)(ws + off); off += (size_t)4096*256*2;
  u16* Vtw = (u16*)(ws + off); off += (size_t)4096*256*2;
  u16* AOw = (u16*)(ws + off); off += (size_t)4096*1024*2;
  u16* kb  = (u16*)(ws + off); off += (size_t)4096*1024*2;
  u16* vb  = (u16*)(ws + off); off += (size_t)4096*1024*2;   // total ~43 MB
  u16* qb  = AOw;   // alias: qb dead before attn_fwd writes AOw

  wcast8<<<7424, 256, 0, stream>>>(query, key, value, w_q, w_k, w_v, w_o,
                                   qb, kb, vb, wqb, wkb, wvb, wob);

  qkv_gemm<<<384, 256, 0, stream>>>(qb, kb, vb, wqb, wkb, wvb,
                                    b_q, b_k, b_v, Qw, Kw, Vtw);

  attn_fwd<<<512, 512, 0, stream>>>(Qw, Kw, Vtw, AOw);

  gemm_o<<<512, 256, 0, stream>>>(AOw, wob, b_o, (float*)d_out);
}